// Round 7
// baseline (189.050 us; speedup 1.0000x reference)
//
#include <hip/hip_runtime.h>

// MoE_52037823758984: out[i] = x[i] @ W_{route[i]}^T + b_{route[i]}
// N = 2,097,152 tokens, D = 10, all f32 (route int32).
//
// R13 = CONTROL EXPERIMENT: same-harness copy-roofline measurement.
//   Ledger: 4 structural theories dead (R8/R9 pipelining, R10 nt/L3,
//   R11 load path, R12 whole-structure). Kernel pinned at ~52us /
//   ~2.5 TB/s fabric with all pipes idle, invariant to everything tried.
//   Before declaring roofline, measure a KNOWN-GOOD pattern on the SAME
//   buffers in the SAME harness (ERRATA #8 discipline: never infer a
//   platform ceiling from your own failed attempts).
//   kernel_launch enqueues TWO dispatches:
//     1. copy_kernel: out[i] = x[i]  -- the 6.29 TB/s float4-copy ubench
//        pattern verbatim (grid-stride, 2048x256, plain coalesced f4).
//        84MB read + 84MB write, same physical buffers as the real op.
//     2. moe_kernel: R10's proven shell (51.6us best) -- overwrites out
//        with correct values, so the bench still PASSES.
//   rocprof reports the two dispatches separately; this round's score is
//   knowingly sacrificed (~+30-55us) for the decisive number.
//   Readout:
//     copy ~25-30us (>=4.5 TB/s) -> memory system fine; MoE's remaining
//       delta = 5-load->store dependency fan-in; attack that next.
//     copy ~45-55us (~2.5 TB/s)  -> buffers cap at 2.5 TB/s in this
//       harness -> MoE kernel is AT the roofline -> declare <<ROOFLINE>>.

#define BLOCK 256
#define D 10
#define WAVE_ROWS 128              // rows per wave
#define F4_PER_WAVE 320            // 128*10/4
#define ROWS_PER_BLOCK 512         // 4 waves
#define COPY_BLOCKS 2048

typedef float f4 __attribute__((ext_vector_type(4)));
typedef float f2 __attribute__((ext_vector_type(2)));

// ---------------------------------------------------------------------
// Dispatch 1: the float4-copy ubench pattern, verbatim, on our buffers.
// ---------------------------------------------------------------------
__global__ __launch_bounds__(BLOCK) void copy_kernel(
    const f4* __restrict__ src, f4* __restrict__ dst, long long nf4)
{
    const long long stride = (long long)gridDim.x * BLOCK;
    for (long long i = (long long)blockIdx.x * BLOCK + threadIdx.x;
         i < nf4; i += stride)
        dst[i] = src[i];
}

// ---------------------------------------------------------------------
// Dispatch 2: R10's proven MoE shell (best scored kernel, 51.6us).
// ---------------------------------------------------------------------
__global__ __launch_bounds__(BLOCK) void moe_kernel(
    const float* __restrict__ x,
    const float* __restrict__ W1,
    const float* __restrict__ b1,
    const float* __restrict__ W2,
    const float* __restrict__ b2,
    const int*   __restrict__ route,
    float*       __restrict__ out,
    int n)
{
    __shared__ f4 lds[(BLOCK / 64) * F4_PER_WAVE];  // 20 KB

    const int lane = threadIdx.x & 63;
    const int wave = threadIdx.x >> 6;
    f4* __restrict__ wlds = lds + wave * F4_PER_WAVE;

    const long long rowbase =
        ((long long)blockIdx.x * (BLOCK / 64) + wave) * WAVE_ROWS;

    if (rowbase + WAVE_ROWS <= n) {
        // ---------- coalesced loads: 5 f4/lane + route int2 ----------
        const f4* __restrict__ xv = (const f4*)(x + rowbase * D);
        f4 bx[5];
        #pragma unroll
        for (int j = 0; j < 5; ++j)
            bx[j] = xv[j * 64 + lane];
        const int2 rt = ((const int2*)(route + rowbase))[lane];

        // ---------- LDS transpose in ----------
        #pragma unroll
        for (int j = 0; j < 5; ++j)
            wlds[j * 64 + lane] = bx[j];
        __builtin_amdgcn_wave_barrier();

        // lane's 2 rows (20 consecutive floats), conflict-free b128 reads
        float xf[2 * D];
        #pragma unroll
        for (int j = 0; j < 5; ++j) {
            f4 t = wlds[lane * 5 + j];
            xf[4 * j + 0] = t.x; xf[4 * j + 1] = t.y;
            xf[4 * j + 2] = t.z; xf[4 * j + 3] = t.w;
        }

        // row-pair vectors: xp[k] = (row0[k], row1[k])
        f2 xp[D];
        #pragma unroll
        for (int k = 0; k < D; ++k)
            xp[k] = (f2){xf[k], xf[D + k]};

        // ---------- packed MLP: both experts, route-select ----------
        float o0[D], o1[D];
        #pragma unroll
        for (int j = 0; j < D; ++j) {
            f2 a0 = (f2){b1[j], b1[j]};
            f2 a1 = (f2){b2[j], b2[j]};
            #pragma unroll
            for (int k = 0; k < D; ++k) {
                const float w1 = W1[j * D + k];
                const float w2 = W2[j * D + k];
                a0 = __builtin_elementwise_fma(xp[k], (f2){w1, w1}, a0);
                a1 = __builtin_elementwise_fma(xp[k], (f2){w2, w2}, a1);
            }
            o0[j] = rt.x ? a1.x : a0.x;
            o1[j] = rt.y ? a1.y : a0.y;
        }

        // ---------- LDS transpose out (lane-private slots, in-order) ----
        __builtin_amdgcn_wave_barrier();  // keep behind the ds_reads above
        {
            f4 t0 = (f4){o0[0], o0[1], o0[2], o0[3]};
            f4 t1 = (f4){o0[4], o0[5], o0[6], o0[7]};
            f4 t2 = (f4){o0[8], o0[9], o1[0], o1[1]};
            f4 t3 = (f4){o1[2], o1[3], o1[4], o1[5]};
            f4 t4 = (f4){o1[6], o1[7], o1[8], o1[9]};
            wlds[lane * 5 + 0] = t0;
            wlds[lane * 5 + 1] = t1;
            wlds[lane * 5 + 2] = t2;
            wlds[lane * 5 + 3] = t3;
            wlds[lane * 5 + 4] = t4;
        }
        __builtin_amdgcn_wave_barrier();

        // ---------- coalesced plain stores (1 KB/instr, proven) ----------
        f4* __restrict__ ov = (f4*)(out + rowbase * D);
        #pragma unroll
        for (int j = 0; j < 5; ++j)
            ov[j * 64 + lane] = wlds[j * 64 + lane];
    } else {
        // ---------- tail path (not hit for N=2097152) ----------
        for (int r = 0; r < 2; ++r) {
            const long long row = rowbase + lane * 2 + r;
            if (row < n) {
                const int sel = route[row];
                for (int j = 0; j < D; ++j) {
                    float y0 = b1[j];
                    float y1 = b2[j];
                    for (int k = 0; k < D; ++k) {
                        const float xk = x[row * D + k];
                        y0 = fmaf(xk, W1[j * D + k], y0);
                        y1 = fmaf(xk, W2[j * D + k], y1);
                    }
                    out[row * D + j] = sel ? y1 : y0;
                }
            }
        }
    }
}

extern "C" void kernel_launch(void* const* d_in, const int* in_sizes, int n_in,
                              void* d_out, int out_size, void* d_ws, size_t ws_size,
                              hipStream_t stream) {
    const float* x     = (const float*)d_in[0];
    const float* W1    = (const float*)d_in[1];
    const float* b1    = (const float*)d_in[2];
    const float* W2    = (const float*)d_in[3];
    const float* b2    = (const float*)d_in[4];
    const int*   route = (const int*)d_in[5];
    float*       out   = (float*)d_out;

    const int n = in_sizes[5];  // N tokens (route length)

    // --- dispatch 1: copy control (out is overwritten by moe below) ---
    const long long nf4 = (long long)n * D / 4;  // 5,242,880 f4
    copy_kernel<<<COPY_BLOCKS, BLOCK, 0, stream>>>(
        (const f4*)x, (f4*)out, nf4);

    // --- dispatch 2: the real op (correct output, R10 proven shell) ---
    const int blocks = (n + ROWS_PER_BLOCK - 1) / ROWS_PER_BLOCK;  // 4096
    moe_kernel<<<blocks, BLOCK, 0, stream>>>(x, W1, b1, W2, b2, route, out, n);
}

// Round 8
// 164.254 us; speedup vs baseline: 1.1510x; 1.1510x over previous
//
#include <hip/hip_runtime.h>

// MoE_52037823758984: out[i] = x[i] @ W_{route[i]}^T + b_{route[i]}
// N = 2,097,152 tokens, D = 10, all f32 (route int32).
//
// R14 = restore R10 (best scored kernel: 163.26us scored / 51.6us kernel)
// after the R13 control experiment settled the investigation.
//
// FINAL ANALYSIS (R13 control, same harness + buffers):
//   copy_kernel (verbatim f4-copy ubench pattern, x->out): 49.5us,
//     FETCH 41MB / WRITE 82MB, 2.54 TB/s fabric.
//   our MoE kernel: 50.5-51.6us, FETCH 45MB / WRITE 82MB -- IDENTICAL
//     signature plus route (8MB) read for free; compute fully hidden.
//   fillBufferAligned (write-only): 6.76 TB/s, 84% of peak -- chip is
//     fine; the READ stream's service rate (~1.7 TB/s for this mix,
//     half-L3-resident) is the binding constraint, and it binds the
//     known-good control exactly as hard as it binds us.
//   Traffic is byte-minimal (x 84MB + route 8MB read, out 82MB write;
//   counters confirm zero amplification). Nothing is removable.
//   => kernel is AT the same-harness empirical roofline (within 2-4% of
//      the copy control). Theory ledger of nulls that corroborate:
//      R8/R9 pipelining, R10 nt-vs-plain, R11 load path, R12 structure.
//
// Shell provenance (proven pieces):
//   - coalesced loads 1KB/instr + LDS transpose in (R2).
//   - packed f32 math: (row0,row1) float2 -> v_pk_fma_f32 (R5).
//   - LDS transpose out + coalesced plain stores (R10: plain == nt
//     bit-identical counters).
//   - 4096 blocks x 256thr, 512 rows/block, 28 VGPR / 20KB LDS ->
//     full occupancy cap; block turnover is the pipelining.

#define BLOCK 256
#define D 10
#define WAVE_ROWS 128              // rows per wave
#define F4_PER_WAVE 320            // 128*10/4
#define ROWS_PER_BLOCK 512         // 4 waves

typedef float f4 __attribute__((ext_vector_type(4)));
typedef float f2 __attribute__((ext_vector_type(2)));

__global__ __launch_bounds__(BLOCK) void moe_kernel(
    const float* __restrict__ x,
    const float* __restrict__ W1,
    const float* __restrict__ b1,
    const float* __restrict__ W2,
    const float* __restrict__ b2,
    const int*   __restrict__ route,
    float*       __restrict__ out,
    int n)
{
    __shared__ f4 lds[(BLOCK / 64) * F4_PER_WAVE];  // 20 KB

    const int lane = threadIdx.x & 63;
    const int wave = threadIdx.x >> 6;
    f4* __restrict__ wlds = lds + wave * F4_PER_WAVE;

    const long long rowbase =
        ((long long)blockIdx.x * (BLOCK / 64) + wave) * WAVE_ROWS;

    if (rowbase + WAVE_ROWS <= n) {
        // ---------- coalesced loads: 5 f4/lane + route int2 ----------
        const f4* __restrict__ xv = (const f4*)(x + rowbase * D);
        f4 bx[5];
        #pragma unroll
        for (int j = 0; j < 5; ++j)
            bx[j] = xv[j * 64 + lane];
        const int2 rt = ((const int2*)(route + rowbase))[lane];

        // ---------- LDS transpose in ----------
        #pragma unroll
        for (int j = 0; j < 5; ++j)
            wlds[j * 64 + lane] = bx[j];
        __builtin_amdgcn_wave_barrier();

        // lane's 2 rows (20 consecutive floats), conflict-free b128 reads
        float xf[2 * D];
        #pragma unroll
        for (int j = 0; j < 5; ++j) {
            f4 t = wlds[lane * 5 + j];
            xf[4 * j + 0] = t.x; xf[4 * j + 1] = t.y;
            xf[4 * j + 2] = t.z; xf[4 * j + 3] = t.w;
        }

        // row-pair vectors: xp[k] = (row0[k], row1[k])
        f2 xp[D];
        #pragma unroll
        for (int k = 0; k < D; ++k)
            xp[k] = (f2){xf[k], xf[D + k]};

        // ---------- packed MLP: both experts, route-select ----------
        float o0[D], o1[D];
        #pragma unroll
        for (int j = 0; j < D; ++j) {
            f2 a0 = (f2){b1[j], b1[j]};
            f2 a1 = (f2){b2[j], b2[j]};
            #pragma unroll
            for (int k = 0; k < D; ++k) {
                const float w1 = W1[j * D + k];
                const float w2 = W2[j * D + k];
                a0 = __builtin_elementwise_fma(xp[k], (f2){w1, w1}, a0);
                a1 = __builtin_elementwise_fma(xp[k], (f2){w2, w2}, a1);
            }
            o0[j] = rt.x ? a1.x : a0.x;
            o1[j] = rt.y ? a1.y : a0.y;
        }

        // ---------- LDS transpose out (lane-private slots, in-order) ----
        __builtin_amdgcn_wave_barrier();  // keep behind the ds_reads above
        {
            f4 t0 = (f4){o0[0], o0[1], o0[2], o0[3]};
            f4 t1 = (f4){o0[4], o0[5], o0[6], o0[7]};
            f4 t2 = (f4){o0[8], o0[9], o1[0], o1[1]};
            f4 t3 = (f4){o1[2], o1[3], o1[4], o1[5]};
            f4 t4 = (f4){o1[6], o1[7], o1[8], o1[9]};
            wlds[lane * 5 + 0] = t0;
            wlds[lane * 5 + 1] = t1;
            wlds[lane * 5 + 2] = t2;
            wlds[lane * 5 + 3] = t3;
            wlds[lane * 5 + 4] = t4;
        }
        __builtin_amdgcn_wave_barrier();

        // ---------- coalesced plain stores (1 KB/instr, proven) ----------
        f4* __restrict__ ov = (f4*)(out + rowbase * D);
        #pragma unroll
        for (int j = 0; j < 5; ++j)
            ov[j * 64 + lane] = wlds[j * 64 + lane];
    } else {
        // ---------- tail path (not hit for N=2097152) ----------
        for (int r = 0; r < 2; ++r) {
            const long long row = rowbase + lane * 2 + r;
            if (row < n) {
                const int sel = route[row];
                for (int j = 0; j < D; ++j) {
                    float y0 = b1[j];
                    float y1 = b2[j];
                    for (int k = 0; k < D; ++k) {
                        const float xk = x[row * D + k];
                        y0 = fmaf(xk, W1[j * D + k], y0);
                        y1 = fmaf(xk, W2[j * D + k], y1);
                    }
                    out[row * D + j] = sel ? y1 : y0;
                }
            }
        }
    }
}

extern "C" void kernel_launch(void* const* d_in, const int* in_sizes, int n_in,
                              void* d_out, int out_size, void* d_ws, size_t ws_size,
                              hipStream_t stream) {
    const float* x     = (const float*)d_in[0];
    const float* W1    = (const float*)d_in[1];
    const float* b1    = (const float*)d_in[2];
    const float* W2    = (const float*)d_in[3];
    const float* b2    = (const float*)d_in[4];
    const int*   route = (const int*)d_in[5];
    float*       out   = (float*)d_out;

    const int n = in_sizes[5];  // N tokens (route length)
    const int blocks = (n + ROWS_PER_BLOCK - 1) / ROWS_PER_BLOCK;  // 4096

    moe_kernel<<<blocks, BLOCK, 0, stream>>>(x, W1, b1, W2, b2, route, out, n);
}